// Round 4
// baseline (1013.158 us; speedup 1.0000x reference)
//
#include <hip/hip_runtime.h>
#include <hip/hip_bf16.h>

#define B_    32
#define CIN   128
#define COUT  128
#define NN    128
#define PPAD  130                   // padded p dimension (1 zero col each side)
#define ROWE  (PPAD * CIN)          // 16640 ushorts per padded row
#define CHUNKS 2080                 // 16B chunks per row (33280 B / 16)

typedef __attribute__((ext_vector_type(8))) short short8;
typedef __attribute__((ext_vector_type(4))) float float4v;

static __device__ inline unsigned short f2bf(float f) {
    union { float f; unsigned u; } v; v.f = f;
    unsigned u = v.u;
    unsigned r = u + 0x7FFFu + ((u >> 16) & 1u);   // RNE
    return (unsigned short)(r >> 16);
}

// async 16B global->LDS copy
static __device__ inline void gll16(const unsigned short* g, unsigned short* l) {
    __builtin_amdgcn_global_load_lds((const __attribute__((address_space(1))) unsigned int*)g,
                                     (__attribute__((address_space(3))) unsigned int*)l,
                                     16, 0, 0);
}

// ---------------------------------------------------------------------------
// x [B][C][N][N] f32 -> xT [B][row][PPAD][128c] bf16, PRE-SWIZZLED:
// channel-slot j (16B) at padded col pp holds channels (j ^ (pp&15))*8 .. +7.
// zero cols pp=0,129. One block per (b,row).
// ---------------------------------------------------------------------------
__global__ __launch_bounds__(256) void xpose_kernel(const float* __restrict__ x,
                                                    unsigned short* __restrict__ xT) {
    int b = blockIdx.x >> 7;
    int i = blockIdx.x & 127;
    __shared__ unsigned short tile[CIN * PPAD];   // [c][p], row stride 130
    int tid = threadIdx.x;
    const float* src = x + ((size_t)(b * CIN) * NN + i) * NN;  // x[b][0][i][0]
    #pragma unroll
    for (int e = 0; e < 64; ++e) {
        int idx = e * 256 + tid;
        int c = idx >> 7;
        int p = idx & 127;
        tile[c * PPAD + p] = f2bf(src[(size_t)c * (NN * NN) + p]);
    }
    __syncthreads();
    unsigned short* dst = xT + (size_t)(b * NN + i) * ROWE;
    #pragma unroll
    for (int e = 0; e < 32; ++e) {
        int pi = e * 256 + tid;          // 0..8191
        int c2 = (pi & 63) * 2;
        int p  = pi >> 6;
        ushort2 v;
        v.x = tile[c2 * PPAD + p];
        v.y = tile[(c2 + 1) * PPAD + p];
        int pp = p + 1;
        int sl = (c2 >> 3) ^ (pp & 15);              // baked XOR swizzle
        *(ushort2*)(dst + (size_t)pp * CIN + sl * 8 + (c2 & 7)) = v;
    }
    if (tid < 128) {                                  // zero pad cols
        dst[tid] = 0;
        dst[(size_t)129 * CIN + tid] = 0;
    }
}

// ---------------------------------------------------------------------------
// kernel [O][C][3][3] f32 -> kT2 [kd][cslot16][o][8c] bf16  (kd = k*3+d)
// A-fragment loads become 256B-contiguous per 16-lane group.
// ---------------------------------------------------------------------------
__global__ __launch_bounds__(256) void ktrans_kernel(const float* __restrict__ kern,
                                                     unsigned short* __restrict__ kT2) {
    int idx = blockIdx.x * 256 + threadIdx.x;     // 0..147455
    if (idx >= COUT * CIN * 9) return;
    int c  = idx & 127;
    int o  = (idx >> 7) & 127;
    int kd = idx >> 14;                           // 0..8
    int k = kd / 3, d = kd % 3;
    float v = kern[(((size_t)o * CIN + c) * 3 + k) * 3 + d];
    kT2[((size_t)(kd * 16 + (c >> 3)) * 128 + o) * 8 + (c & 7)] = f2bf(v);
}

// ---------------------------------------------------------------------------
// main v4: 256 blocks (1/CU), each owns 16 output rows of one image.
// 4-slot LDS ring of padded swizzled rows; async global_load_lds staging of
// row i+2 hidden under row i's MFMAs; one barrier per step.
// 8 waves: wave tile 64 o x 32 px per step.
// ---------------------------------------------------------------------------
__global__ __launch_bounds__(512, 2) void conv_mfma4_kernel(const unsigned short* __restrict__ xT,
                                                            const unsigned short* __restrict__ kT2,
                                                            float* __restrict__ out) {
    __shared__ unsigned short xs[4 * ROWE];   // 133,120 B -> 1 block/CU

    int b    = blockIdx.x >> 3;
    int r0   = (blockIdx.x & 7) << 4;
    int tid  = threadIdx.x;
    int lane = tid & 63;
    int wave = tid >> 6;
    int ob  = (wave >> 2) * 64;    // o base
    int pb  = (wave & 3) * 32;     // px base
    int l15 = lane & 15;
    int lg  = lane >> 4;           // 0..3

    const unsigned short* xrow_base = xT + (size_t)b * NN * ROWE;

    // ---- prologue: local rows -1,0,1 -> ring slots 0,1,2 ----
    #pragma unroll
    for (int lr = -1; lr <= 1; ++lr) {
        int grow = r0 + lr;
        unsigned short* sb = &xs[(size_t)(lr + 1) * ROWE];
        if (grow >= 0) {                                  // block-uniform
            const unsigned short* src = xrow_base + (size_t)grow * ROWE;
            #pragma unroll
            for (int s = 0; s < 4; ++s)
                gll16(src + (size_t)(s * 512 + tid) * 8, sb + (size_t)(s * 512 + tid) * 8);
            if (tid < 32)
                gll16(src + (size_t)(2048 + tid) * 8, sb + (size_t)(2048 + tid) * 8);
        } else {
            #pragma unroll
            for (int s = 0; s < 4; ++s)
                *(short8*)&sb[(size_t)(s * 512 + tid) * 8] = (short8)(0);
            if (tid < 32)
                *(short8*)&sb[(size_t)(2048 + tid) * 8] = (short8)(0);
        }
    }
    __syncthreads();

    for (int i = 0; i < 16; ++i) {
        // ---- issue async stage of local row i+2 -> slot (i+3)&3 ----
        if (i < 15) {
            int grow = r0 + i + 2;
            unsigned short* sb = &xs[(size_t)((i + 3) & 3) * ROWE];
            if (grow < NN) {                              // block-uniform
                const unsigned short* src = xrow_base + (size_t)grow * ROWE;
                #pragma unroll
                for (int s = 0; s < 4; ++s)
                    gll16(src + (size_t)(s * 512 + tid) * 8, sb + (size_t)(s * 512 + tid) * 8);
                if (tid < 32)
                    gll16(src + (size_t)(2048 + tid) * 8, sb + (size_t)(2048 + tid) * 8);
            } else {
                #pragma unroll
                for (int s = 0; s < 4; ++s)
                    *(short8*)&sb[(size_t)(s * 512 + tid) * 8] = (short8)(0);
                if (tid < 32)
                    *(short8*)&sb[(size_t)(2048 + tid) * 8] = (short8)(0);
            }
        }

        // ---- compute output row r0+i ----
        float4v acc[4][2];
        #pragma unroll
        for (int m = 0; m < 4; ++m) {
            acc[m][0] = (float4v)(0.0f);
            acc[m][1] = (float4v)(0.0f);
        }

        #pragma unroll
        for (int kd = 0; kd < 9; ++kd) {
            const int k = kd / 3, d = kd % 3;
            const unsigned short* sbase = &xs[(size_t)((i + k) & 3) * ROWE];
            #pragma unroll
            for (int cc = 0; cc < 4; ++cc) {
                const int cslot = cc * 4 + lg;
                short8 a[4], bt[2];
                #pragma unroll
                for (int m = 0; m < 4; ++m)
                    a[m] = *(const short8*)(kT2 +
                        ((size_t)((kd * 16 + cslot) * 128) + ob + m * 16 + l15) * 8);
                int pp0 = pb + l15 + d;                   // 0..129 (padded, always valid)
                int pp1 = pp0 + 16;
                bt[0] = *(const short8*)(sbase + (size_t)pp0 * CIN + (cslot ^ (pp0 & 15)) * 8);
                bt[1] = *(const short8*)(sbase + (size_t)pp1 * CIN + (cslot ^ (pp1 & 15)) * 8);
                #pragma unroll
                for (int m = 0; m < 4; ++m) {
                    acc[m][0] = __builtin_amdgcn_mfma_f32_16x16x32_bf16(a[m], bt[0], acc[m][0], 0, 0, 0);
                    acc[m][1] = __builtin_amdgcn_mfma_f32_16x16x32_bf16(a[m], bt[1], acc[m][1], 0, 0, 0);
                }
            }
        }

        // ---- store row (D: col=lane&15 -> px, row=(lane>>4)*4+r -> o) ----
        float* op = out + (size_t)b * COUT * NN * NN + (size_t)(r0 + i) * NN;
        #pragma unroll
        for (int m = 0; m < 4; ++m) {
            #pragma unroll
            for (int n = 0; n < 2; ++n) {
                int p = pb + n * 16 + l15;
                #pragma unroll
                for (int r = 0; r < 4; ++r) {
                    int o = ob + m * 16 + lg * 4 + r;
                    op[(size_t)o * (NN * NN) + p] = acc[m][n][r];
                }
            }
        }
        __syncthreads();
    }
}

// ---------------------------------------------------------------------------
// fallback: naive direct conv (only if workspace too small)
// ---------------------------------------------------------------------------
__global__ __launch_bounds__(256) void conv_naive_kernel(const float* __restrict__ x,
                                                         const float* __restrict__ kern,
                                                         float* __restrict__ out) {
    size_t idx = (size_t)blockIdx.x * 256 + threadIdx.x;
    int p = idx & 127;
    size_t t = idx >> 7;
    int i = t & 127; t >>= 7;
    int o = t & 127;
    int b = (int)(t >> 7);
    float s = 0.f;
    for (int c = 0; c < CIN; ++c) {
        #pragma unroll
        for (int k = 0; k < 3; ++k) {
            int r = i + k - 1;
            if (r < 0 || r >= NN) continue;
            #pragma unroll
            for (int d = 0; d < 3; ++d) {
                int q = p + d - 1;
                if (q < 0 || q >= NN) continue;
                s += kern[(((size_t)o * CIN + c) * 3 + k) * 3 + d]
                   * x[(((size_t)b * CIN + c) * NN + r) * NN + q];
            }
        }
    }
    out[idx] = s;
}

extern "C" void kernel_launch(void* const* d_in, const int* in_sizes, int n_in,
                              void* d_out, int out_size, void* d_ws, size_t ws_size,
                              hipStream_t stream) {
    const float* x    = (const float*)d_in[0];
    const float* kern = (const float*)d_in[1];
    float* out = (float*)d_out;

    const size_t xT_bytes  = (size_t)B_ * NN * ROWE * 2;        // 136,314,880
    const size_t kT_bytes  = (size_t)9 * 16 * 128 * 8 * 2;      //     294,912

    if (ws_size >= xT_bytes + kT_bytes) {
        unsigned short* xT  = (unsigned short*)d_ws;
        unsigned short* kT2 = (unsigned short*)((char*)d_ws + xT_bytes);
        hipLaunchKernelGGL(xpose_kernel, dim3(B_ * NN), dim3(256), 0, stream, x, xT);
        hipLaunchKernelGGL(ktrans_kernel, dim3(576), dim3(256), 0, stream, kern, kT2);
        hipLaunchKernelGGL(conv_mfma4_kernel, dim3(256), dim3(512), 0, stream, xT, kT2, out);
    } else {
        hipLaunchKernelGGL(conv_naive_kernel, dim3(67108864 / 256), dim3(256), 0, stream,
                           x, kern, out);
    }
}

// Round 6
// 283.934 us; speedup vs baseline: 3.5683x; 3.5683x over previous
//
#include <hip/hip_runtime.h>
#include <hip/hip_bf16.h>

#define B_    32
#define CIN   128
#define COUT  128
#define NN    128
#define PPAD  130                   // padded p dimension (1 zero col each side)
#define ROWE  (PPAD * CIN)          // 16640 ushorts per padded xT row

// v6 LDS tile: 4 rows x 66 cols x 128 ch, chunked as [r][j][slot16][8ch]
#define JCOLS 66
#define CHROW (JCOLS * 16)          // 1056 chunks per row
#define CH5   (4 * CHROW)           // 4224 chunks per block tile

typedef __attribute__((ext_vector_type(8))) short short8;
typedef __attribute__((ext_vector_type(4))) float float4v;

static __device__ inline unsigned short f2bf(float f) {
    union { float f; unsigned u; } v; v.f = f;
    unsigned u = v.u;
    unsigned r = u + 0x7FFFu + ((u >> 16) & 1u);   // RNE
    return (unsigned short)(r >> 16);
}

// async 16B global->LDS copy (dest: readfirstlane(base)+lane*16 — callers
// MUST keep the branch wave-uniform / first-active-lane == 0)
static __device__ inline void gll16(const unsigned short* g, unsigned short* l) {
    __builtin_amdgcn_global_load_lds((const __attribute__((address_space(1))) unsigned int*)g,
                                     (__attribute__((address_space(3))) unsigned int*)l,
                                     16, 0, 0);
}

// ---------------------------------------------------------------------------
// x [B][C][N][N] f32 -> xT [B][row][PPAD][128c] bf16, PRE-SWIZZLED:
// 16B chunk at (pp, slot j) holds channels (j ^ (pp&15))*8 .. +7.
// zero cols pp=0,129. One block per (b,row).
// ---------------------------------------------------------------------------
__global__ __launch_bounds__(256) void xpose_kernel(const float* __restrict__ x,
                                                    unsigned short* __restrict__ xT) {
    int b = blockIdx.x >> 7;
    int i = blockIdx.x & 127;
    __shared__ unsigned short tile[CIN * PPAD];   // [c][p], row stride 130
    int tid = threadIdx.x;
    const float* src = x + ((size_t)(b * CIN) * NN + i) * NN;  // x[b][0][i][0]
    #pragma unroll
    for (int e = 0; e < 64; ++e) {
        int idx = e * 256 + tid;
        int c = idx >> 7;
        int p = idx & 127;
        tile[c * PPAD + p] = f2bf(src[(size_t)c * (NN * NN) + p]);
    }
    __syncthreads();
    unsigned short* dst = xT + (size_t)(b * NN + i) * ROWE;
    #pragma unroll
    for (int e = 0; e < 32; ++e) {
        int pi = e * 256 + tid;          // 0..8191
        int c2 = (pi & 63) * 2;
        int p  = pi >> 6;
        ushort2 v;
        v.x = tile[c2 * PPAD + p];
        v.y = tile[(c2 + 1) * PPAD + p];
        int pp = p + 1;
        int sl = (c2 >> 3) ^ (pp & 15);              // baked XOR swizzle
        *(ushort2*)(dst + (size_t)pp * CIN + sl * 8 + (c2 & 7)) = v;
    }
    if (tid < 128) {                                  // zero pad cols
        dst[tid] = 0;
        dst[(size_t)129 * CIN + tid] = 0;
    }
}

// ---------------------------------------------------------------------------
// kernel [O][C][3][3] f32 -> kT2 [kd][cslot16][o][8c] bf16  (kd = k*3+d)
// ---------------------------------------------------------------------------
__global__ __launch_bounds__(256) void ktrans_kernel(const float* __restrict__ kern,
                                                     unsigned short* __restrict__ kT2) {
    int idx = blockIdx.x * 256 + threadIdx.x;     // 0..147455
    if (idx >= COUT * CIN * 9) return;
    int c  = idx & 127;
    int o  = (idx >> 7) & 127;
    int kd = idx >> 14;                           // 0..8
    int k = kd / 3, d = kd % 3;
    float v = kern[(((size_t)o * CIN + c) * 3 + k) * 3 + d];
    kT2[((size_t)(kd * 16 + (c >> 3)) * 128 + o) * 8 + (c & 7)] = f2bf(v);
}

// ---------------------------------------------------------------------------
// main v6: block = 2 output rows x 64 px x 128 o. 512 thr (8 waves), LDS
// 67.6 KB -> 2 blocks/CU (4 waves/SIMD). x staged ONCE per block via async
// global_load_lds with CLAMPED row (full-wave issue, no divergence); halo
// rows outside [0,128) zeroed afterwards with plain ds_writes (block-uniform
// branch, border blocks only). A-frags from kT2 (L2-hot 288 KB).
// wave tile: 64 o x 32 px on one of the 2 rows.
// ---------------------------------------------------------------------------
__global__ __launch_bounds__(512, 4) void conv_mfma6_kernel(const unsigned short* __restrict__ xT,
                                                            const unsigned short* __restrict__ kT2,
                                                            float* __restrict__ out) {
    __shared__ unsigned short xs[CH5 * 8];   // 67,584 B

    // bijective XCD swizzle: 4096 blocks, 8 XCDs, 512-block contiguous slabs
    int wg = blockIdx.x;
    int lb = (wg & 7) * 512 + (wg >> 3);
    int b  = lb >> 7;            // image
    int t  = lb & 127;
    int ph = t >> 6;             // px half (0/1): global px base = ph*64
    int rp = t & 63;             // row pair
    const int pb0 = ph * 64;

    int tid  = threadIdx.x;
    int lane = tid & 63;
    int wave = tid >> 6;
    int wo = wave >> 2;            // o half (0/1)
    int wr = (wave >> 1) & 1;      // row of pair
    int wp = wave & 1;             // px 32-half
    int ob  = wo * 64;
    int l15 = lane & 15;
    int lg  = lane >> 4;           // 0..3

    // ---- stage 4 x-rows (rp*2-1 .. rp*2+2), cols pb0..pb0+65, once ----
    // grow clamped so every lane of a participating wave issues gll16
    // (global_load_lds dest = firstlane base + lane*16: divergence forbidden)
    {
        const unsigned short* xrow_base = xT + (size_t)b * NN * ROWE;
        #pragma unroll
        for (int s = 0; s < 9; ++s) {
            int W = s * 512 + tid;
            if (W < CH5) {                       // full waves only (4224 = 66*64)
                int r    = W / CHROW;            // 0..3
                int rem  = W - r * CHROW;        // j*16 + slot
                int grow = rp * 2 - 1 + r;       // -1..128
                int growc = grow < 0 ? 0 : (grow > NN - 1 ? NN - 1 : grow);
                const unsigned short* src = xrow_base + (size_t)growc * ROWE
                                          + ((size_t)pb0 + (rem >> 4)) * CIN
                                          + (rem & 15) * 8;
                gll16(src, xs + (size_t)W * 8);
            }
        }
    }
    __syncthreads();   // drains vmcnt -> staged data visible

    // ---- zero halo rows outside the image (block-uniform branches) ----
    if (rp == 0) {
        for (int W = tid; W < CHROW; W += 512)                    // row r=0
            *(short8*)(xs + (size_t)W * 8) = (short8)(0);
    }
    if (rp == 63) {
        for (int W = 3 * CHROW + tid; W < 4 * CHROW; W += 512)    // row r=3
            *(short8*)(xs + (size_t)W * 8) = (short8)(0);
    }
    if (rp == 0 || rp == 63) __syncthreads();

    float4v acc[4][2];
    #pragma unroll
    for (int m = 0; m < 4; ++m) {
        acc[m][0] = (float4v)(0.0f);
        acc[m][1] = (float4v)(0.0f);
    }

    #pragma unroll
    for (int kd = 0; kd < 9; ++kd) {
        const int k = kd / 3, d = kd % 3;
        const unsigned short* srow = xs + (size_t)(wr + k) * CHROW * 8;  // LDS row
        #pragma unroll
        for (int cc = 0; cc < 4; ++cc) {
            const int cslot = cc * 4 + lg;
            short8 a[4], bt[2];
            #pragma unroll
            for (int m = 0; m < 4; ++m)
                a[m] = *(const short8*)(kT2 +
                    ((size_t)((kd * 16 + cslot) * 128) + ob + m * 16 + l15) * 8);
            int j0 = wp * 32 + l15 + d;          // 0..65 (local col)
            int j1 = j0 + 16;
            bt[0] = *(const short8*)(srow + ((size_t)j0 * 16 + (cslot ^ (j0 & 15))) * 8);
            bt[1] = *(const short8*)(srow + ((size_t)j1 * 16 + (cslot ^ (j1 & 15))) * 8);
            #pragma unroll
            for (int m = 0; m < 4; ++m) {
                acc[m][0] = __builtin_amdgcn_mfma_f32_16x16x32_bf16(a[m], bt[0], acc[m][0], 0, 0, 0);
                acc[m][1] = __builtin_amdgcn_mfma_f32_16x16x32_bf16(a[m], bt[1], acc[m][1], 0, 0, 0);
            }
        }
    }

    // store: D col = lane&15 -> px, row = (lane>>4)*4 + r -> o
    int row = rp * 2 + wr;
    float* op = out + (size_t)b * COUT * NN * NN + (size_t)row * NN;
    #pragma unroll
    for (int m = 0; m < 4; ++m) {
        #pragma unroll
        for (int n = 0; n < 2; ++n) {
            int p = pb0 + wp * 32 + n * 16 + l15;
            #pragma unroll
            for (int r = 0; r < 4; ++r) {
                int o = ob + m * 16 + lg * 4 + r;
                op[(size_t)o * (NN * NN) + p] = acc[m][n][r];
            }
        }
    }
}

// ---------------------------------------------------------------------------
// fallback: naive direct conv (only if workspace too small)
// ---------------------------------------------------------------------------
__global__ __launch_bounds__(256) void conv_naive_kernel(const float* __restrict__ x,
                                                         const float* __restrict__ kern,
                                                         float* __restrict__ out) {
    size_t idx = (size_t)blockIdx.x * 256 + threadIdx.x;
    int p = idx & 127;
    size_t t = idx >> 7;
    int i = t & 127; t >>= 7;
    int o = t & 127;
    int b = (int)(t >> 7);
    float s = 0.f;
    for (int c = 0; c < CIN; ++c) {
        #pragma unroll
        for (int k = 0; k < 3; ++k) {
            int r = i + k - 1;
            if (r < 0 || r >= NN) continue;
            #pragma unroll
            for (int d = 0; d < 3; ++d) {
                int q = p + d - 1;
                if (q < 0 || q >= NN) continue;
                s += kern[(((size_t)o * CIN + c) * 3 + k) * 3 + d]
                   * x[(((size_t)b * CIN + c) * NN + r) * NN + q];
            }
        }
    }
    out[idx] = s;
}

extern "C" void kernel_launch(void* const* d_in, const int* in_sizes, int n_in,
                              void* d_out, int out_size, void* d_ws, size_t ws_size,
                              hipStream_t stream) {
    const float* x    = (const float*)d_in[0];
    const float* kern = (const float*)d_in[1];
    float* out = (float*)d_out;

    const size_t xT_bytes  = (size_t)B_ * NN * ROWE * 2;        // 136,314,880
    const size_t kT_bytes  = (size_t)9 * 16 * 128 * 8 * 2;      //     294,912

    if (ws_size >= xT_bytes + kT_bytes) {
        unsigned short* xT  = (unsigned short*)d_ws;
        unsigned short* kT2 = (unsigned short*)((char*)d_ws + xT_bytes);
        hipLaunchKernelGGL(xpose_kernel, dim3(B_ * NN), dim3(256), 0, stream, x, xT);
        hipLaunchKernelGGL(ktrans_kernel, dim3(576), dim3(256), 0, stream, kern, kT2);
        hipLaunchKernelGGL(conv_mfma6_kernel, dim3(4096), dim3(512), 0, stream, xT, kT2, out);
    } else {
        hipLaunchKernelGGL(conv_naive_kernel, dim3(67108864 / 256), dim3(256), 0, stream,
                           x, kern, out);
    }
}